// Round 5
// baseline (128.020 us; speedup 1.0000x reference)
//
#include <hip/hip_runtime.h>
#include <hip/hip_bf16.h>

#define B_ 8
#define Q_ 128
#define K_ 256
#define D_ 512
#define TWOLOG2E 2.8853900817779268f
#define SCALE 0.044194173824159216f   // 1/sqrt(512)
#define L2E 1.4426950408889634f
#define MASKVAL (-44194173.824159216f) // -1e9 * SCALE

typedef __attribute__((ext_vector_type(8))) short frag8;   // 8 bf16
typedef __attribute__((ext_vector_type(4))) float f32x4;

__device__ __forceinline__ float fexp2(float x) {
  float r;
  asm("v_exp_f32 %0, %1" : "=v"(r) : "v"(x));
  return r;
}
__device__ __forceinline__ float frcp(float x) {
  float r;
  asm("v_rcp_f32 %0, %1" : "=v"(r) : "v"(x));
  return r;
}
__device__ __forceinline__ unsigned f2bf_u(float x) {
  unsigned u = __float_as_uint(x);
  return (u + 0x7FFFu + ((u >> 16) & 1u)) >> 16;
}
__device__ __forceinline__ unsigned short f2bf(float x) {
  return (unsigned short)f2bf_u(x);
}
__device__ __forceinline__ unsigned packbf(float lo, float hi) {
  return f2bf_u(lo) | (f2bf_u(hi) << 16);
}

// ---------------- Kernel 1: fused convert + MFMA projection GEMM ----------------
// C[m][n] = sum_d X[m][d] * W1[sel(m)*512 + d][n], X = concat(query,key).
// q-rows (m<1024): qp[m][n] = C*2log2e                 (row-major [b][q][h])
// k-rows         : kpbT[b][n][k] = (C+b1[n])*2log2e    (transposed, k-contiguous)
// Tiles 32m x 64n, BK=64, 256 threads (4 waves), grid (8, 96) = 768 blocks.
// fp32->bf16 conversion fused into LDS staging; W1 transposed in-LDS.
__global__ __launch_bounds__(256) void gemm_kernel(
    const float* __restrict__ query, const float* __restrict__ key,
    const float* __restrict__ W1, const float* __restrict__ b1,
    float* __restrict__ qp, float* __restrict__ kpbT) {
  __shared__ short As[32 * 64];   // [m][d] bf16, chunk-swizzled
  __shared__ short Bs[64 * 64];   // [n][d] bf16, chunk-swizzled
  const int t = threadIdx.x;
  const int m0 = blockIdx.y * 32;
  const int n0 = blockIdx.x * 64;
  const bool is_k = (m0 >= B_ * Q_);
  const float* X = is_k ? key : query;
  const int xrow0 = is_k ? (m0 - B_ * Q_) : m0;
  const float* Wb = W1 + (is_k ? (size_t)D_ * D_ : 0);

  // A staging: thread -> row am = t>>3, d-chunk ac = t&7 (8 floats)
  const int am = t >> 3;
  const int ac = t & 7;
  const float* gA = X + (size_t)(xrow0 + am) * D_ + ac * 8;
  short* aw = As + am * 64 + ((ac ^ (am & 7)) * 8);

  // B staging: thread -> d-pair bd=(t&31)*2, n-chunk bn=(t>>5)*8 (8 n)
  const int bd = (t & 31) * 2;
  const int bn = t >> 5;  // n-chunk index 0..7; n = bn*8 + j
  const float* gB0 = Wb + (size_t)bd * D_ + n0 + bn * 8;
  const float* gB1 = gB0 + D_;
  const int bchunk = bd >> 3;        // chunk 0..7
  const int bsub = bd & 7;           // even offset in chunk

  // fragment offsets
  const int l = t & 63;
  const int w = t >> 6;
  const int lr = l & 15;
  const int kg = l >> 4;
  const int key8 = lr & 7;
  int aoff[2][2], boff[2];
#pragma unroll
  for (int kk = 0; kk < 2; ++kk) {
    const int cpos = ((kg + kk * 4) ^ key8) * 8;
#pragma unroll
    for (int mt = 0; mt < 2; ++mt) aoff[mt][kk] = (mt * 16 + lr) * 64 + cpos;
    boff[kk] = (w * 16 + lr) * 64 + cpos;
  }

  f32x4 acc[2];
  acc[0] = (f32x4){0.f, 0.f, 0.f, 0.f};
  acc[1] = (f32x4){0.f, 0.f, 0.f, 0.f};

  for (int k0 = 0; k0 < D_; k0 += 64) {
    // global loads (fp32)
    float4 a0 = *(const float4*)(gA + k0);
    float4 a1 = *(const float4*)(gA + k0 + 4);
    const float* p0 = gB0 + (size_t)k0 * D_;
    const float* p1 = gB1 + (size_t)k0 * D_;
    float4 b00 = *(const float4*)(p0);
    float4 b01 = *(const float4*)(p0 + 4);
    float4 b10 = *(const float4*)(p1);
    float4 b11 = *(const float4*)(p1 + 4);
    __syncthreads();
    // A: 8 bf16 contiguous
    union { frag8 f; unsigned short u[8]; } av;
    av.u[0] = f2bf(a0.x); av.u[1] = f2bf(a0.y); av.u[2] = f2bf(a0.z); av.u[3] = f2bf(a0.w);
    av.u[4] = f2bf(a1.x); av.u[5] = f2bf(a1.y); av.u[6] = f2bf(a1.z); av.u[7] = f2bf(a1.w);
    *(frag8*)aw = av.f;
    // B: transposed writes, b32 = (d, d+1) pair per n
    {
      float r0[8] = {b00.x, b00.y, b00.z, b00.w, b01.x, b01.y, b01.z, b01.w};
      float r1[8] = {b10.x, b10.y, b10.z, b10.w, b11.x, b11.y, b11.z, b11.w};
#pragma unroll
      for (int j = 0; j < 8; ++j) {
        const int n = bn * 8 + j;
        const int epos = ((bchunk ^ j) * 8) + bsub;  // (n&7)==j
        *(unsigned*)(Bs + n * 64 + epos) = packbf(r0[j], r1[j]);
      }
    }
    __syncthreads();
#pragma unroll
    for (int kk = 0; kk < 2; ++kk) {
      frag8 bf = *(const frag8*)(Bs + boff[kk]);
#pragma unroll
      for (int mt = 0; mt < 2; ++mt) {
        frag8 af = *(const frag8*)(As + aoff[mt][kk]);
        acc[mt] = __builtin_amdgcn_mfma_f32_16x16x32_bf16(af, bf, acc[mt], 0, 0, 0);
      }
    }
  }

  const int col = n0 + w * 16 + lr;   // n (h)
  if (is_k) {
    const float bc = b1[col];
#pragma unroll
    for (int mt = 0; mt < 2; ++mt) {
      const int krow = m0 - B_ * Q_ + mt * 16 + kg * 4;  // 4 consecutive k
      const int bb = krow >> 8;
      const int kk0 = krow & 255;
      float4 v;
      v.x = (acc[mt][0] + bc) * TWOLOG2E;
      v.y = (acc[mt][1] + bc) * TWOLOG2E;
      v.z = (acc[mt][2] + bc) * TWOLOG2E;
      v.w = (acc[mt][3] + bc) * TWOLOG2E;
      *(float4*)&kpbT[((size_t)bb * D_ + col) * K_ + kk0] = v;
    }
  } else {
#pragma unroll
    for (int mt = 0; mt < 2; ++mt) {
#pragma unroll
      for (int i = 0; i < 4; ++i) {
        const int row = m0 + mt * 16 + kg * 4 + i;
        qp[(size_t)row * D_ + col] = acc[mt][i] * TWOLOG2E;
      }
    }
  }
}

// ---------------- Kernel 2: fused tanh-score + softmax + PV ----------------
// 1024 threads = 16 waves, 4 q-rows/block, grid (32, 8).
// Wave w: kc = w&3 (k-range kc*64+lane), hq = w>>2 (h-range hq*128).
__global__ __launch_bounds__(1024) void attn_kernel(
    const float* __restrict__ qp, const float* __restrict__ kpbT,
    const float* __restrict__ value, const int* __restrict__ mask,
    const float* __restrict__ w2,
    float* __restrict__ out_vec, float* __restrict__ out_w) {
  __shared__ float smem_p[16 * 256];  // partials: [w][q(4)][64]
  __shared__ float pw[4 * 256];       // final weights: [q][k]
  const int b = blockIdx.y;
  const int q0 = blockIdx.x * 4;
  const int t = threadIdx.x;
  const int lane = t & 63;
  const int w = __builtin_amdgcn_readfirstlane(t >> 6);  // 0..15
  const int kc = w & 3;
  const int hq = w >> 2;

  // ---- phase 1: partial sums of w2[h] * r(h,k,q) over this wave's h-range
  {
    const float* pk = kpbT + ((size_t)b * D_ + hq * 128) * K_ + kc * 64 + lane;
    const float* q_0 = qp + (size_t)(b * Q_ + q0 + 0) * D_ + hq * 128;
    const float* q_1 = qp + (size_t)(b * Q_ + q0 + 1) * D_ + hq * 128;
    const float* q_2 = qp + (size_t)(b * Q_ + q0 + 2) * D_ + hq * 128;
    const float* q_3 = qp + (size_t)(b * Q_ + q0 + 3) * D_ + hq * 128;
    const float* w2h = w2 + hq * 128;

    float a0 = 0.f, a1 = 0.f, a2 = 0.f, a3 = 0.f;
    for (int h = 0; h < 128; h += 8) {
      float kv[8];
#pragma unroll
      for (int j = 0; j < 8; ++j) kv[j] = pk[(size_t)(h + j) * K_];
#pragma unroll
      for (int j = 0; j < 8; ++j) {
        const float wv = w2h[h + j];
        const float r0 = frcp(fexp2(q_0[h + j] + kv[j]) + 1.f);
        const float r1 = frcp(fexp2(q_1[h + j] + kv[j]) + 1.f);
        const float r2 = frcp(fexp2(q_2[h + j] + kv[j]) + 1.f);
        const float r3 = frcp(fexp2(q_3[h + j] + kv[j]) + 1.f);
        a0 = fmaf(wv, r0, a0);
        a1 = fmaf(wv, r1, a1);
        a2 = fmaf(wv, r2, a2);
        a3 = fmaf(wv, r3, a3);
      }
    }
    smem_p[w * 256 + 0 * 64 + lane] = a0;
    smem_p[w * 256 + 1 * 64 + lane] = a1;
    smem_p[w * 256 + 2 * 64 + lane] = a2;
    smem_p[w * 256 + 3 * 64 + lane] = a3;
  }
  __syncthreads();

  // ---- phase 2: combine + softmax; wave qi handles q-row q0+qi
  if (w < 4) {
    float sw = 0.f;
#pragma unroll
    for (int m = 0; m < 8; ++m) sw += w2[lane + 64 * m];
#pragma unroll
    for (int off = 32; off; off >>= 1) sw += __shfl_xor(sw, off);

    float s[4];
#pragma unroll
    for (int r = 0; r < 4; ++r) {  // r = kc
      float p = smem_p[(0 * 4 + r) * 256 + w * 64 + lane] +
                smem_p[(1 * 4 + r) * 256 + w * 64 + lane] +
                smem_p[(2 * 4 + r) * 256 + w * 64 + lane] +
                smem_p[(3 * 4 + r) * 256 + w * 64 + lane];
      const int mk = mask[b * K_ + r * 64 + lane];
      s[r] = mk ? MASKVAL : fmaf(-2.f, p, sw) * SCALE;
    }
    float mx = fmaxf(fmaxf(s[0], s[1]), fmaxf(s[2], s[3]));
#pragma unroll
    for (int off = 32; off; off >>= 1) mx = fmaxf(mx, __shfl_xor(mx, off));
    float e[4], sum = 0.f;
#pragma unroll
    for (int r = 0; r < 4; ++r) {
      e[r] = fexp2((s[r] - mx) * L2E);
      sum += e[r];
    }
#pragma unroll
    for (int off = 32; off; off >>= 1) sum += __shfl_xor(sum, off);
    const float inv = frcp(sum);
    float* ow = out_w + (size_t)(b * Q_ + q0 + w) * K_;
#pragma unroll
    for (int r = 0; r < 4; ++r) {
      const float p = e[r] * inv;
      pw[w * 256 + r * 64 + lane] = p;
      ow[r * 64 + lane] = p;
    }
  }
  __syncthreads();

  // ---- phase 3: PV. thread t -> col = t&511, q-pair qq = t>>9
  const int col = t & 511;
  const int qq = t >> 9;
  float o0 = 0.f, o1 = 0.f;
  const float* vb = value + (size_t)b * K_ * D_;
  for (int k = 0; k < K_; k += 4) {
    const float4 p0 = *(const float4*)&pw[(qq * 2 + 0) * 256 + k];
    const float4 p1 = *(const float4*)&pw[(qq * 2 + 1) * 256 + k];
    const float v0 = vb[(size_t)(k + 0) * D_ + col];
    const float v1 = vb[(size_t)(k + 1) * D_ + col];
    const float v2 = vb[(size_t)(k + 2) * D_ + col];
    const float v3 = vb[(size_t)(k + 3) * D_ + col];
    o0 = fmaf(p0.x, v0, fmaf(p0.y, v1, fmaf(p0.z, v2, fmaf(p0.w, v3, o0))));
    o1 = fmaf(p1.x, v0, fmaf(p1.y, v1, fmaf(p1.z, v2, fmaf(p1.w, v3, o1))));
  }
  out_vec[(size_t)(b * Q_ + q0 + qq * 2 + 0) * D_ + col] = o0;
  out_vec[(size_t)(b * Q_ + q0 + qq * 2 + 1) * D_ + col] = o1;
}

extern "C" void kernel_launch(void* const* d_in, const int* in_sizes, int n_in,
                              void* d_out, int out_size, void* d_ws, size_t ws_size,
                              hipStream_t stream) {
  const float* query = (const float*)d_in[0];
  const float* key   = (const float*)d_in[1];
  const float* value = (const float*)d_in[2];
  const int*   mask  = (const int*)d_in[3];
  const float* W1    = (const float*)d_in[4];
  const float* b1    = (const float*)d_in[5];
  const float* w2    = (const float*)d_in[6];

  float* out_vec = (float*)d_out;                   // (8,128,512)
  float* out_w   = out_vec + (size_t)B_ * Q_ * D_;  // (8,128,256)

  float* qp   = (float*)d_ws;                       // 2 MB fp32 [b][q][h]
  float* kpbT = qp + (size_t)B_ * Q_ * D_;          // 4 MB fp32 [b][h][k]

  gemm_kernel<<<dim3(8, 96), 256, 0, stream>>>(query, key, W1, b1, qp, kpbT);
  attn_kernel<<<dim3(Q_ / 4, B_), 1024, 0, stream>>>(qp, kpbT, value, mask, w2,
                                                     out_vec, out_w);
}

// Round 6
// 113.280 us; speedup vs baseline: 1.1301x; 1.1301x over previous
//
#include <hip/hip_runtime.h>
#include <hip/hip_bf16.h>

#define B_ 8
#define Q_ 128
#define K_ 256
#define D_ 512
#define TWOLOG2E 2.8853900817779268f
#define SCALE 0.044194173824159216f   // 1/sqrt(512)
#define L2E 1.4426950408889634f
#define MASKVAL (-44194173.824159216f) // -1e9 * SCALE

typedef __attribute__((ext_vector_type(8))) short frag8;   // 8 bf16
typedef __attribute__((ext_vector_type(4))) float f32x4;

__device__ __forceinline__ float fexp2(float x) {
  float r;
  asm("v_exp_f32 %0, %1" : "=v"(r) : "v"(x));
  return r;
}
__device__ __forceinline__ float frcp(float x) {
  float r;
  asm("v_rcp_f32 %0, %1" : "=v"(r) : "v"(x));
  return r;
}
__device__ __forceinline__ unsigned f2bf_u(float x) {
  unsigned u = __float_as_uint(x);
  return (u + 0x7FFFu + ((u >> 16) & 1u)) >> 16;
}
__device__ __forceinline__ unsigned short f2bf(float x) {
  return (unsigned short)f2bf_u(x);
}
__device__ __forceinline__ unsigned packbf(float lo, float hi) {
  return f2bf_u(lo) | (f2bf_u(hi) << 16);
}

// ---------------- Kernel 1: fused convert + MFMA projection GEMM ----------------
// C[m][n] = sum_d X[m][d] * W1[sel(m)*512 + d][n], X = concat(query,key).
// q-rows: qp[m][n]      = exp(2*C)           ("Eq", row-major [b][q][h])
// k-rows: kpbT[b][n][k] = exp(2*(C+b1[n]))   ("Ek", transposed, k-contiguous)
// Tiles 32m x 64n, BK=64, 256 threads (4 waves), grid (8, 96).
// B-staging: coalesced float4 row loads + packed-b32 transposed LDS writes
// into padded [n][72] tile (<=2-way banks = free).
__global__ __launch_bounds__(256) void gemm_kernel(
    const float* __restrict__ query, const float* __restrict__ key,
    const float* __restrict__ W1, const float* __restrict__ b1,
    float* __restrict__ qp, float* __restrict__ kpbT) {
  __shared__ short As[32 * 64];   // [m][d], chunk xor-swizzled
  __shared__ short Bs[64 * 72];   // [n][d], +8 pad
  const int t = threadIdx.x;
  const int m0 = blockIdx.y * 32;
  const int n0 = blockIdx.x * 64;
  const bool is_k = (m0 >= B_ * Q_);
  const float* X = is_k ? key : query;
  const int xrow0 = is_k ? (m0 - B_ * Q_) : m0;
  const float* Wb = W1 + (is_k ? (size_t)D_ * D_ : 0);

  // A staging: thread -> row am = t>>3, d-chunk ac = t&7 (8 floats)
  const int am = t >> 3;
  const int ac = t & 7;
  const float* gA = X + (size_t)(xrow0 + am) * D_ + ac * 8;
  short* aw = As + am * 64 + ((ac ^ (am & 7)) * 8);

  // B staging: prow = t>>4 (0..15), n4 = (t&15)*4.
  // d-pairs handled: prow and prow+16  (d rows 2p, 2p+1).
  const int prow = t >> 4;
  const int n4 = (t & 15) * 4;
  const float* gB = Wb + n0 + n4;

  // fragment offsets
  const int l = t & 63;
  const int w = t >> 6;
  const int lr = l & 15;
  const int kg = l >> 4;
  const int key8 = lr & 7;
  int aoff[2][2], boff[2];
#pragma unroll
  for (int kk = 0; kk < 2; ++kk) {
    const int cposA = ((kg + kk * 4) ^ key8) * 8;
#pragma unroll
    for (int mt = 0; mt < 2; ++mt) aoff[mt][kk] = (mt * 16 + lr) * 64 + cposA;
    boff[kk] = (w * 16 + lr) * 72 + (kg + kk * 4) * 8;
  }

  f32x4 acc[2];
  acc[0] = (f32x4){0.f, 0.f, 0.f, 0.f};
  acc[1] = (f32x4){0.f, 0.f, 0.f, 0.f};

  for (int k0 = 0; k0 < D_; k0 += 64) {
    float4 a0 = *(const float4*)(gA + k0);
    float4 a1 = *(const float4*)(gA + k0 + 4);
    float4 w00 = *(const float4*)(gB + (size_t)(k0 + 2 * prow) * D_);
    float4 w01 = *(const float4*)(gB + (size_t)(k0 + 2 * prow + 1) * D_);
    float4 w10 = *(const float4*)(gB + (size_t)(k0 + 2 * prow + 32) * D_);
    float4 w11 = *(const float4*)(gB + (size_t)(k0 + 2 * prow + 33) * D_);
    __syncthreads();
    {
      union { frag8 f; unsigned short u[8]; } av;
      av.u[0] = f2bf(a0.x); av.u[1] = f2bf(a0.y); av.u[2] = f2bf(a0.z); av.u[3] = f2bf(a0.w);
      av.u[4] = f2bf(a1.x); av.u[5] = f2bf(a1.y); av.u[6] = f2bf(a1.z); av.u[7] = f2bf(a1.w);
      *(frag8*)aw = av.f;
    }
    {
      float lo0[4] = {w00.x, w00.y, w00.z, w00.w};
      float hi0[4] = {w01.x, w01.y, w01.z, w01.w};
      float lo1[4] = {w10.x, w10.y, w10.z, w10.w};
      float hi1[4] = {w11.x, w11.y, w11.z, w11.w};
#pragma unroll
      for (int j = 0; j < 4; ++j) {
        *(unsigned*)(Bs + (n4 + j) * 72 + 2 * prow) = packbf(lo0[j], hi0[j]);
        *(unsigned*)(Bs + (n4 + j) * 72 + 2 * (prow + 16)) = packbf(lo1[j], hi1[j]);
      }
    }
    __syncthreads();
#pragma unroll
    for (int kk = 0; kk < 2; ++kk) {
      frag8 bf = *(const frag8*)(Bs + boff[kk]);
#pragma unroll
      for (int mt = 0; mt < 2; ++mt) {
        frag8 af = *(const frag8*)(As + aoff[mt][kk]);
        acc[mt] = __builtin_amdgcn_mfma_f32_16x16x32_bf16(af, bf, acc[mt], 0, 0, 0);
      }
    }
  }

  const int col = n0 + w * 16 + lr;   // n (h)
  if (is_k) {
    const float bc = b1[col];
#pragma unroll
    for (int mt = 0; mt < 2; ++mt) {
      const int krow = m0 - B_ * Q_ + mt * 16 + kg * 4;  // 4 consecutive k
      const int bb = krow >> 8;
      const int kk0 = krow & 255;
      float4 v;
      v.x = fexp2((acc[mt][0] + bc) * TWOLOG2E);
      v.y = fexp2((acc[mt][1] + bc) * TWOLOG2E);
      v.z = fexp2((acc[mt][2] + bc) * TWOLOG2E);
      v.w = fexp2((acc[mt][3] + bc) * TWOLOG2E);
      *(float4*)&kpbT[((size_t)bb * D_ + col) * K_ + kk0] = v;
    }
  } else {
#pragma unroll
    for (int mt = 0; mt < 2; ++mt) {
#pragma unroll
      for (int i = 0; i < 4; ++i) {
        const int row = m0 + mt * 16 + kg * 4 + i;
        qp[(size_t)row * D_ + col] = fexp2(acc[mt][i] * TWOLOG2E);
      }
    }
  }
}

// ---------------- Kernel 2: fused tanh-score + softmax + PV ----------------
// qp holds Eq = e^{2 qproj}; kpbT holds Ek = e^{2(kproj+b1)}.
// tanh term: r = 1/(Eq*Ek + 1);  sum w2*tanh = sum w2 - 2*sum w2*r.
// 1024 threads = 16 waves, 4 q-rows/block, grid (32, 8).
// Wave w: kc = w&3 (k = kc*64+lane), hq = w>>2 (h-range hq*128).
__global__ __launch_bounds__(1024) void attn_kernel(
    const float* __restrict__ qp, const float* __restrict__ kpbT,
    const float* __restrict__ value, const int* __restrict__ mask,
    const float* __restrict__ w2,
    float* __restrict__ out_vec, float* __restrict__ out_w) {
  __shared__ float smem_p[16 * 256];  // partials: [w][q(4)][64]
  __shared__ float pw[4 * 256];       // final weights: [q][k]
  const int b = blockIdx.y;
  const int q0 = blockIdx.x * 4;
  const int t = threadIdx.x;
  const int lane = t & 63;
  const int w = __builtin_amdgcn_readfirstlane(t >> 6);  // 0..15
  const int kc = w & 3;
  const int hq = w >> 2;

  // ---- phase 1: partial sums of w2[h] * r(h,k,q) over this wave's h-range
  {
    const float* pk = kpbT + ((size_t)b * D_ + hq * 128) * K_ + kc * 64 + lane;
    const float* q_0 = qp + (size_t)(b * Q_ + q0 + 0) * D_ + hq * 128;
    const float* q_1 = qp + (size_t)(b * Q_ + q0 + 1) * D_ + hq * 128;
    const float* q_2 = qp + (size_t)(b * Q_ + q0 + 2) * D_ + hq * 128;
    const float* q_3 = qp + (size_t)(b * Q_ + q0 + 3) * D_ + hq * 128;
    const float* w2h = w2 + hq * 128;

    float a0 = 0.f, a1 = 0.f, a2 = 0.f, a3 = 0.f;
    for (int h = 0; h < 128; h += 8) {
      float kv[8];
#pragma unroll
      for (int j = 0; j < 8; ++j) kv[j] = pk[(size_t)(h + j) * K_];
      float4 e0a = *(const float4*)(q_0 + h), e0b = *(const float4*)(q_0 + h + 4);
      float4 e1a = *(const float4*)(q_1 + h), e1b = *(const float4*)(q_1 + h + 4);
      float4 e2a = *(const float4*)(q_2 + h), e2b = *(const float4*)(q_2 + h + 4);
      float4 e3a = *(const float4*)(q_3 + h), e3b = *(const float4*)(q_3 + h + 4);
      float4 wa = *(const float4*)(w2h + h), wb = *(const float4*)(w2h + h + 4);
      float E0[8] = {e0a.x, e0a.y, e0a.z, e0a.w, e0b.x, e0b.y, e0b.z, e0b.w};
      float E1[8] = {e1a.x, e1a.y, e1a.z, e1a.w, e1b.x, e1b.y, e1b.z, e1b.w};
      float E2[8] = {e2a.x, e2a.y, e2a.z, e2a.w, e2b.x, e2b.y, e2b.z, e2b.w};
      float E3[8] = {e3a.x, e3a.y, e3a.z, e3a.w, e3b.x, e3b.y, e3b.z, e3b.w};
      float WV[8] = {wa.x, wa.y, wa.z, wa.w, wb.x, wb.y, wb.z, wb.w};
#pragma unroll
      for (int j = 0; j < 8; ++j) {
        const float r0 = frcp(fmaf(E0[j], kv[j], 1.f));
        const float r1 = frcp(fmaf(E1[j], kv[j], 1.f));
        const float r2 = frcp(fmaf(E2[j], kv[j], 1.f));
        const float r3 = frcp(fmaf(E3[j], kv[j], 1.f));
        a0 = fmaf(WV[j], r0, a0);
        a1 = fmaf(WV[j], r1, a1);
        a2 = fmaf(WV[j], r2, a2);
        a3 = fmaf(WV[j], r3, a3);
      }
    }
    smem_p[w * 256 + 0 * 64 + lane] = a0;
    smem_p[w * 256 + 1 * 64 + lane] = a1;
    smem_p[w * 256 + 2 * 64 + lane] = a2;
    smem_p[w * 256 + 3 * 64 + lane] = a3;
  }
  __syncthreads();

  // ---- phase 2: combine + softmax; wave qi handles q-row q0+qi
  if (w < 4) {
    float sw = 0.f;
#pragma unroll
    for (int m = 0; m < 8; ++m) sw += w2[lane + 64 * m];
#pragma unroll
    for (int off = 32; off; off >>= 1) sw += __shfl_xor(sw, off);

    float s[4];
#pragma unroll
    for (int r = 0; r < 4; ++r) {  // r = kc
      float p = smem_p[(0 * 4 + r) * 256 + w * 64 + lane] +
                smem_p[(1 * 4 + r) * 256 + w * 64 + lane] +
                smem_p[(2 * 4 + r) * 256 + w * 64 + lane] +
                smem_p[(3 * 4 + r) * 256 + w * 64 + lane];
      const int mk = mask[b * K_ + r * 64 + lane];
      s[r] = mk ? MASKVAL : fmaf(-2.f, p, sw) * SCALE;
    }
    float mx = fmaxf(fmaxf(s[0], s[1]), fmaxf(s[2], s[3]));
#pragma unroll
    for (int off = 32; off; off >>= 1) mx = fmaxf(mx, __shfl_xor(mx, off));
    float e[4], sum = 0.f;
#pragma unroll
    for (int r = 0; r < 4; ++r) {
      e[r] = fexp2((s[r] - mx) * L2E);
      sum += e[r];
    }
#pragma unroll
    for (int off = 32; off; off >>= 1) sum += __shfl_xor(sum, off);
    const float inv = frcp(sum);
    float* ow = out_w + (size_t)(b * Q_ + q0 + w) * K_;
#pragma unroll
    for (int r = 0; r < 4; ++r) {
      const float p = e[r] * inv;
      pw[w * 256 + r * 64 + lane] = p;
      ow[r * 64 + lane] = p;
    }
  }
  __syncthreads();

  // ---- phase 3: PV. thread t -> col = t&511, q-pair qq = t>>9
  const int col = t & 511;
  const int qq = t >> 9;
  float o0 = 0.f, o1 = 0.f;
  const float* vb = value + (size_t)b * K_ * D_;
  for (int k = 0; k < K_; k += 4) {
    const float4 p0 = *(const float4*)&pw[(qq * 2 + 0) * 256 + k];
    const float4 p1 = *(const float4*)&pw[(qq * 2 + 1) * 256 + k];
    const float v0 = vb[(size_t)(k + 0) * D_ + col];
    const float v1 = vb[(size_t)(k + 1) * D_ + col];
    const float v2 = vb[(size_t)(k + 2) * D_ + col];
    const float v3 = vb[(size_t)(k + 3) * D_ + col];
    o0 = fmaf(p0.x, v0, fmaf(p0.y, v1, fmaf(p0.z, v2, fmaf(p0.w, v3, o0))));
    o1 = fmaf(p1.x, v0, fmaf(p1.y, v1, fmaf(p1.z, v2, fmaf(p1.w, v3, o1))));
  }
  out_vec[(size_t)(b * Q_ + q0 + qq * 2 + 0) * D_ + col] = o0;
  out_vec[(size_t)(b * Q_ + q0 + qq * 2 + 1) * D_ + col] = o1;
}

extern "C" void kernel_launch(void* const* d_in, const int* in_sizes, int n_in,
                              void* d_out, int out_size, void* d_ws, size_t ws_size,
                              hipStream_t stream) {
  const float* query = (const float*)d_in[0];
  const float* key   = (const float*)d_in[1];
  const float* value = (const float*)d_in[2];
  const int*   mask  = (const int*)d_in[3];
  const float* W1    = (const float*)d_in[4];
  const float* b1    = (const float*)d_in[5];
  const float* w2    = (const float*)d_in[6];

  float* out_vec = (float*)d_out;                   // (8,128,512)
  float* out_w   = out_vec + (size_t)B_ * Q_ * D_;  // (8,128,256)

  float* qp   = (float*)d_ws;                       // 2 MB fp32 Eq [b][q][h]
  float* kpbT = qp + (size_t)B_ * Q_ * D_;          // 4 MB fp32 Ek [b][h][k]

  gemm_kernel<<<dim3(8, 96), 256, 0, stream>>>(query, key, W1, b1, qp, kpbT);
  attn_kernel<<<dim3(Q_ / 4, B_), 1024, 0, stream>>>(qp, kpbT, value, mask, w2,
                                                     out_vec, out_w);
}